// Round 3
// baseline (857.473 us; speedup 1.0000x reference)
//
#include <hip/hip_runtime.h>
#include <hip/hip_bf16.h>

// KNN: points (8,4096,3) f32, features (8,4096,64) f32.
// out (8,4096,16,128) f32: [center 64 | knn 64] per (b, i, k).
// Neighbors = 16 nearest excluding self, ascending distance, ties -> lower index.
//
// Structure: 512 threads = 64 queries x 8 candidate-partitions (NSUB).
// Lazy top-16: cheap threshold test per candidate; passing candidates go to an
// 8-slot per-thread LDS pending queue; the 16-deep insert network runs only at
// wave-collective flushes (__any(cnt>=8)) -> ~27 flushes instead of 512 inserts.

#define BATCH 8
#define NPTS 4096
#define FDIM 64
#define KNN 16
#define QPB 64
#define NSUB 8
#define CPL (NPTS / NSUB)      // 512 candidates per thread
#define THREADS (QPB * NSUB)   // 512
#define PQCAP 8                // pending slots used
#define PQSTRIDE 9             // uint2 slots per thread row (+1 pad)

#define INF __builtin_inff()

// branch-free sorted insert of (d, j) into ascending bd/bi[16].
// Exact: strict < everywhere; equal d lands AFTER existing (higher j loses,
// and within a lane all stored j are < incoming j). d=INF is a no-op.
__device__ __forceinline__ void insert16(float d, int j, float bd[KNN], int bi[KNN]) {
    bool c[KNN];
#pragma unroll
    for (int p = 0; p < KNN; ++p) c[p] = d < bd[p];   // sorted => c[p-1] implies c[p]
#pragma unroll
    for (int p = KNN - 1; p > 0; --p) {
        bd[p] = c[p] ? (c[p - 1] ? bd[p - 1] : d) : bd[p];
        bi[p] = c[p] ? (c[p - 1] ? bi[p - 1] : j) : bi[p];
    }
    bd[0] = c[0] ? d : bd[0];
    bi[0] = c[0] ? j : bi[0];
}

__global__ __launch_bounds__(THREADS, 4)
void knn_kernel(const float* __restrict__ points,
                const float* __restrict__ features,
                float* __restrict__ out) {
    // LDS union (phases separated by __syncthreads):
    //  scan : pend uint2[512*9]                       [0, 36864)
    //  merge: smd f32 [16][NSUB][QPB]                 [0, 32768)   (s*8+sub)*64+q
    //         smi u16 [16][NSUB][QPB]                 [32768, 49152)
    //  write: sidx u16[QPB][KNN]                      [49152, 51200)
    __shared__ __align__(16) unsigned char smem[51200];
    uint2* pend = (uint2*)smem;
    float* smd = (float*)smem;
    unsigned short* smi = (unsigned short*)(smem + 32768);
    unsigned short* sidx = (unsigned short*)(smem + 49152);

    const int tid = threadIdx.x;
    const int b = blockIdx.x >> 6;
    const int qbase = (blockIdx.x & 63) << 6;
    const float* pb = points + (size_t)b * NPTS * 3;

    const int q = tid & (QPB - 1);     // query within block (lane)
    const int sub = tid >> 6;          // partition, uniform per wave
    const int qg0 = qbase + q;

    const float qx = pb[qg0 * 3 + 0];
    const float qy = pb[qg0 * 3 + 1];
    const float qz = pb[qg0 * 3 + 2];

    float bd[KNN];
    int bi[KNN];
#pragma unroll
    for (int s = 0; s < KNN; ++s) { bd[s] = INF; bi[s] = 0; }

    int cnt = 0;
    const int pbase = tid * PQSTRIDE;

    // wave-uniform candidate base -> scalar loads of candidate points
    const int jbase = __builtin_amdgcn_readfirstlane(sub) * CPL;
    const float* __restrict__ ps = pb + (size_t)jbase * 3;

    for (int jj = 0; jj < CPL; jj += 2) {
#pragma unroll
        for (int u = 0; u < 2; ++u) {
            const int jo = jj + u;
            const int j = jbase + jo;
            const float px = ps[jo * 3 + 0];
            const float py = ps[jo * 3 + 1];
            const float pz = ps[jo * 3 + 2];
            const float dx = qx - px;
            const float dy = qy - py;
            const float dz = qz - pz;
            // match numpy: ((dx*dx + dy*dy) + dz*dz), no FMA contraction
            const float d = __fadd_rn(__fadd_rn(__fmul_rn(dx, dx), __fmul_rn(dy, dy)),
                                      __fmul_rn(dz, dz));
            const bool pass = (d < bd[KNN - 1]) && (j != qg0);
            if (pass) {
                pend[pbase + cnt] = make_uint2(__float_as_uint(d), (unsigned)j);
                cnt++;
            }
            if (__any(cnt >= PQCAP)) {
                // flush ALL pending in this wave (keeps lanes correlated)
#pragma unroll
                for (int s = 0; s < PQCAP; ++s) {
                    const uint2 e = pend[pbase + s];
                    const float dd = (cnt > s) ? __uint_as_float(e.x) : INF;
                    insert16(dd, (int)e.y, bd, bi);
                }
                cnt = 0;
            }
        }
    }
    {
        // final drain (no-op lanes insert INF)
#pragma unroll
        for (int s = 0; s < PQCAP; ++s) {
            const uint2 e = pend[pbase + s];
            const float dd = (cnt > s) ? __uint_as_float(e.x) : INF;
            insert16(dd, (int)e.y, bd, bi);
        }
    }

    __syncthreads();   // all pend rows dead before smd/smi overwrite the region

    // dump per-(q,sub) sorted lists; [s][sub][q] layout: addr = lane + const
    // -> conflict-free (baseline's 1.65M bank conflicts were this dump)
#pragma unroll
    for (int s = 0; s < KNN; ++s) {
        smd[(s * NSUB + sub) * QPB + q] = bd[s];
        smi[(s * NSUB + sub) * QPB + q] = (unsigned short)bi[s];
    }
    __syncthreads();

    // 8-way tournament merge, one thread per query; ties -> lower m (= lower j
    // range, since sub m covers j in [m*CPL,(m+1)*CPL))
    if (tid < QPB) {
        int pp[NSUB];
#pragma unroll
        for (int m = 0; m < NSUB; ++m) pp[m] = 0;
        for (int s = 0; s < KNN; ++s) {
            float bestd = INF;
            int besta = 0, sel = 0;
#pragma unroll
            for (int m = 0; m < NSUB; ++m) {
                const int a = (pp[m] * NSUB + m) * QPB + tid;
                const float dm = (pp[m] < KNN) ? smd[a] : INF;
                const bool w = dm < bestd;     // strict: earlier m wins ties
                bestd = w ? dm : bestd;
                besta = w ? a : besta;
                sel = w ? m : sel;
            }
            sidx[tid * KNN + s] = smi[besta];
#pragma unroll
            for (int m = 0; m < NSUB; ++m) pp[m] += (sel == m);
        }
    }
    __syncthreads();

    // gather + write: 64 q x 16 k x 32 float4 = 32768 float4 per block
    const float* __restrict__ fb = features + (size_t)b * NPTS * FDIM;
    float* __restrict__ ob = out + (size_t)b * NPTS * (KNN * 2 * FDIM);
#pragma unroll 2
    for (int it = 0; it < 64; ++it) {
        const int flat = it * THREADS + tid;
        const int c4 = flat & 31;          // float4 column 0..31
        const int k = (flat >> 5) & 15;
        const int qq = flat >> 9;          // 0..63
        const int qg = qbase + qq;
        const int row = (c4 < 16) ? qg : (int)sidx[qq * KNN + k];
        const float4 v = *(const float4*)(fb + (size_t)row * FDIM + ((c4 & 15) << 2));
        *(float4*)(ob + (((size_t)(qg * KNN + k)) << 7) + (c4 << 2)) = v;
    }
}

extern "C" void kernel_launch(void* const* d_in, const int* in_sizes, int n_in,
                              void* d_out, int out_size, void* d_ws, size_t ws_size,
                              hipStream_t stream) {
    const float* points = (const float*)d_in[0];
    const float* features = (const float*)d_in[1];
    float* out = (float*)d_out;
    const int grid = BATCH * (NPTS / QPB);   // 512 blocks
    knn_kernel<<<dim3(grid), dim3(THREADS), 0, stream>>>(points, features, out);
}

// Round 4
// 621.294 us; speedup vs baseline: 1.3801x; 1.3801x over previous
//
#include <hip/hip_runtime.h>
#include <hip/hip_bf16.h>

// KNN: points (8,4096,3) f32, features (8,4096,64) f32.
// out (8,4096,16,128) f32: [center 64 | knn 64] per (b, i, k).
// Neighbors = 16 nearest excluding self, ascending distance, ties -> lower index.
//
// Structure: 512 threads = 64 queries x 8 candidate-partitions (NSUB).
// Lazy top-16: cheap threshold test per candidate; passing candidates go to an
// 8-slot per-thread LDS pending queue; the 16-deep insert network runs only at
// wave-collective flushes (__any(cnt>=8)).
//
// R3 post-mortem: __launch_bounds__(512,4) made the allocator target 64 VGPRs
// (= 512/8) and SPILL bd[]/bi[] to scratch -> 1.7 GB of HBM scratch writes,
// kernel 630us. Fix: (512,2) -> cap 256 VGPRs, no spill. LDS still allows
// 2 blocks/CU (4 waves/SIMD).

#define BATCH 8
#define NPTS 4096
#define FDIM 64
#define KNN 16
#define QPB 64
#define NSUB 8
#define CPL (NPTS / NSUB)      // 512 candidates per thread
#define THREADS (QPB * NSUB)   // 512
#define PQCAP 8                // pending slots used
#define PQSTRIDE 9             // uint2 slots per thread row (+1 pad)

#define INF __builtin_inff()

// branch-free sorted insert of (d, j) into ascending bd/bi[16].
// Exact: strict < everywhere; equal d lands AFTER existing (higher j loses,
// and within a lane all stored j are < incoming j). d=INF is a no-op.
__device__ __forceinline__ void insert16(float d, int j, float bd[KNN], int bi[KNN]) {
    bool c[KNN];
#pragma unroll
    for (int p = 0; p < KNN; ++p) c[p] = d < bd[p];   // sorted => c[p-1] implies c[p]
#pragma unroll
    for (int p = KNN - 1; p > 0; --p) {
        bd[p] = c[p] ? (c[p - 1] ? bd[p - 1] : d) : bd[p];
        bi[p] = c[p] ? (c[p - 1] ? bi[p - 1] : j) : bi[p];
    }
    bd[0] = c[0] ? d : bd[0];
    bi[0] = c[0] ? j : bi[0];
}

__global__ __launch_bounds__(THREADS, 2)
void knn_kernel(const float* __restrict__ points,
                const float* __restrict__ features,
                float* __restrict__ out) {
    // LDS union (phases separated by __syncthreads):
    //  scan : pend uint2[512*9]                       [0, 36864)
    //  merge: smd f32 [16][NSUB][QPB]                 [0, 32768)   (s*8+sub)*64+q
    //         smi u16 [16][NSUB][QPB]                 [32768, 49152)
    //  write: sidx u16[QPB][KNN]                      [49152, 51200)
    __shared__ __align__(16) unsigned char smem[51200];
    uint2* pend = (uint2*)smem;
    float* smd = (float*)smem;
    unsigned short* smi = (unsigned short*)(smem + 32768);
    unsigned short* sidx = (unsigned short*)(smem + 49152);

    const int tid = threadIdx.x;
    const int b = blockIdx.x >> 6;
    const int qbase = (blockIdx.x & 63) << 6;
    const float* pb = points + (size_t)b * NPTS * 3;

    const int q = tid & (QPB - 1);     // query within block (lane)
    const int sub = tid >> 6;          // partition, uniform per wave
    const int qg0 = qbase + q;

    const float qx = pb[qg0 * 3 + 0];
    const float qy = pb[qg0 * 3 + 1];
    const float qz = pb[qg0 * 3 + 2];

    float bd[KNN];
    int bi[KNN];
#pragma unroll
    for (int s = 0; s < KNN; ++s) { bd[s] = INF; bi[s] = 0; }

    int cnt = 0;
    const int pbase = tid * PQSTRIDE;

    // wave-uniform candidate base -> scalar loads of candidate points
    const int jbase = __builtin_amdgcn_readfirstlane(sub) * CPL;
    const float* __restrict__ ps = pb + (size_t)jbase * 3;

    for (int jj = 0; jj < CPL; jj += 2) {
#pragma unroll
        for (int u = 0; u < 2; ++u) {
            const int jo = jj + u;
            const int j = jbase + jo;
            const float px = ps[jo * 3 + 0];
            const float py = ps[jo * 3 + 1];
            const float pz = ps[jo * 3 + 2];
            const float dx = qx - px;
            const float dy = qy - py;
            const float dz = qz - pz;
            // match numpy: ((dx*dx + dy*dy) + dz*dz), no FMA contraction
            const float d = __fadd_rn(__fadd_rn(__fmul_rn(dx, dx), __fmul_rn(dy, dy)),
                                      __fmul_rn(dz, dz));
            const bool pass = (d < bd[KNN - 1]) && (j != qg0);
            if (pass) {
                pend[pbase + cnt] = make_uint2(__float_as_uint(d), (unsigned)j);
                cnt++;
            }
            if (__any(cnt >= PQCAP)) {
                // flush ALL pending in this wave (keeps lanes correlated)
#pragma unroll
                for (int s = 0; s < PQCAP; ++s) {
                    const uint2 e = pend[pbase + s];
                    const float dd = (cnt > s) ? __uint_as_float(e.x) : INF;
                    insert16(dd, (int)e.y, bd, bi);
                }
                cnt = 0;
            }
        }
    }
    {
        // final drain (no-op lanes insert INF)
#pragma unroll
        for (int s = 0; s < PQCAP; ++s) {
            const uint2 e = pend[pbase + s];
            const float dd = (cnt > s) ? __uint_as_float(e.x) : INF;
            insert16(dd, (int)e.y, bd, bi);
        }
    }

    __syncthreads();   // all pend rows dead before smd/smi overwrite the region

    // dump per-(q,sub) sorted lists; [s][sub][q] layout: addr = lane + const
    // -> conflict-free
#pragma unroll
    for (int s = 0; s < KNN; ++s) {
        smd[(s * NSUB + sub) * QPB + q] = bd[s];
        smi[(s * NSUB + sub) * QPB + q] = (unsigned short)bi[s];
    }
    __syncthreads();

    // 8-way tournament merge, one thread per query; ties -> lower m (= lower j
    // range, since sub m covers j in [m*CPL,(m+1)*CPL))
    if (tid < QPB) {
        int pp[NSUB];
#pragma unroll
        for (int m = 0; m < NSUB; ++m) pp[m] = 0;
        for (int s = 0; s < KNN; ++s) {
            float bestd = INF;
            int besta = 0, sel = 0;
#pragma unroll
            for (int m = 0; m < NSUB; ++m) {
                const int a = (pp[m] * NSUB + m) * QPB + tid;
                const float dm = (pp[m] < KNN) ? smd[a] : INF;
                const bool w = dm < bestd;     // strict: earlier m wins ties
                bestd = w ? dm : bestd;
                besta = w ? a : besta;
                sel = w ? m : sel;
            }
            sidx[tid * KNN + s] = smi[besta];
#pragma unroll
            for (int m = 0; m < NSUB; ++m) pp[m] += (sel == m);
        }
    }
    __syncthreads();

    // gather + write: 64 q x 16 k x 32 float4 = 32768 float4 per block
    const float* __restrict__ fb = features + (size_t)b * NPTS * FDIM;
    float* __restrict__ ob = out + (size_t)b * NPTS * (KNN * 2 * FDIM);
#pragma unroll 2
    for (int it = 0; it < 64; ++it) {
        const int flat = it * THREADS + tid;
        const int c4 = flat & 31;          // float4 column 0..31
        const int k = (flat >> 5) & 15;
        const int qq = flat >> 9;          // 0..63
        const int qg = qbase + qq;
        const int row = (c4 < 16) ? qg : (int)sidx[qq * KNN + k];
        const float4 v = *(const float4*)(fb + (size_t)row * FDIM + ((c4 & 15) << 2));
        *(float4*)(ob + (((size_t)(qg * KNN + k)) << 7) + (c4 << 2)) = v;
    }
}

extern "C" void kernel_launch(void* const* d_in, const int* in_sizes, int n_in,
                              void* d_out, int out_size, void* d_ws, size_t ws_size,
                              hipStream_t stream) {
    const float* points = (const float*)d_in[0];
    const float* features = (const float*)d_in[1];
    float* out = (float*)d_out;
    const int grid = BATCH * (NPTS / QPB);   // 512 blocks
    knn_kernel<<<dim3(grid), dim3(THREADS), 0, stream>>>(points, features, out);
}

// Round 5
// 518.164 us; speedup vs baseline: 1.6548x; 1.1990x over previous
//
#include <hip/hip_runtime.h>

// KNN: points (8,4096,3) f32, features (8,4096,64) f32.
// out (8,4096,16,128) f32: [center 64 | knn 64] per (b, i, k).
// Neighbors = 16 nearest excluding self, ascending distance, ties -> lower index.
//
// R4 post-mortem: bd+bi+LDS-queue exceeded the 128-VGPR cap -> 530MB of scratch
// spill per launch (WRITE_SIZE 795MB vs 262MB output) + 4-way-conflicting
// uint2 queue. R5 restructure: pass 1 tracks DISTANCES ONLY (16 VGPR state,
// no spill); a rescan recovers indices of candidates with d <= per-query d16,
// exact order via packed u64 key (d_bits<<32)|j.

#define BATCH 8
#define NPTS 4096
#define FDIM 64
#define KNN 16
#define QPB 64
#define NSUB 8
#define CPL (NPTS / NSUB)      // 512 candidates per thread
#define THREADS (QPB * NSUB)   // 512
#define LCAP 32                // per-query recovery-list capacity (>= 16 + ties)
#define INF __builtin_inff()

// branch-free sorted insert of d into ascending bd[16] (values only).
// bd sorted => (d < bd[p-1]) implies (d < bd[p]).
__device__ __forceinline__ void insert16d(float d, float bd[KNN]) {
    bool c[KNN];
#pragma unroll
    for (int p = 0; p < KNN; ++p) c[p] = d < bd[p];
#pragma unroll
    for (int p = KNN - 1; p > 0; --p)
        bd[p] = c[p] ? (c[p - 1] ? bd[p - 1] : d) : bd[p];
    bd[0] = c[0] ? d : bd[0];
}

__global__ __launch_bounds__(THREADS, 4)
void knn_kernel(const float* __restrict__ points,
                const float* __restrict__ features,
                float* __restrict__ out) {
    // LDS (35328 B total):
    //  [0, 32768)     union { smd f32[16][NSUB][QPB] (P1/P2) ;
    //                         slist u64[LCAP][QPB]   (P3/P4) }   // [i][q]: conflict-free
    //  [32768, 33024) d16  f32[QPB]
    //  [33024, 33280) scnt u32[QPB]
    //  [33280, 35328) sidx u16[QPB][KNN]
    __shared__ __align__(16) unsigned char smem[35328];
    float* smd = (float*)smem;
    unsigned long long* slist = (unsigned long long*)smem;
    float* d16 = (float*)(smem + 32768);
    unsigned* scnt = (unsigned*)(smem + 33024);
    unsigned short* sidx = (unsigned short*)(smem + 33280);

    const int tid = threadIdx.x;
    const int b = blockIdx.x >> 6;
    const int qbase = (blockIdx.x & 63) << 6;
    const float* pb = points + (size_t)b * NPTS * 3;

    const int q = tid & (QPB - 1);     // query within block (lane)
    const int sub = tid >> 6;          // partition, uniform per wave
    const int qg0 = qbase + q;

    if (tid < QPB) scnt[tid] = 0;      // ready before P3 (barriers intervene)

    const float qx = pb[qg0 * 3 + 0];
    const float qy = pb[qg0 * 3 + 1];
    const float qz = pb[qg0 * 3 + 2];

    // ---- P1: per-(q,sub) sorted top-16 distances over this sub's 512 candidates
    float bd[KNN];
#pragma unroll
    for (int s = 0; s < KNN; ++s) bd[s] = INF;

    const int jbase = __builtin_amdgcn_readfirstlane(sub) * CPL;
    const float* __restrict__ ps = pb + (size_t)jbase * 3;

    for (int jj = 0; jj < CPL; jj += 2) {
#pragma unroll
        for (int u = 0; u < 2; ++u) {
            const int jo = jj + u;
            const int j = jbase + jo;
            const float px = ps[jo * 3 + 0];
            const float py = ps[jo * 3 + 1];
            const float pz = ps[jo * 3 + 2];
            const float dx = qx - px;
            const float dy = qy - py;
            const float dz = qz - pz;
            // match numpy: ((dx*dx + dy*dy) + dz*dz), no FMA contraction
            float d = __fadd_rn(__fadd_rn(__fmul_rn(dx, dx), __fmul_rn(dy, dy)),
                                __fmul_rn(dz, dz));
            if (j == qg0) d = INF;     // exclude self
            if (d < bd[KNN - 1]) insert16d(d, bd);
        }
    }

    // dump distance lists; [s][sub][q]: addr = lane + const -> conflict-free
#pragma unroll
    for (int s = 0; s < KNN; ++s)
        smd[(s * NSUB + sub) * QPB + q] = bd[s];
    __syncthreads();

    // ---- P2: 8-way tournament merge (values only) -> d16 = 16th smallest
    if (tid < QPB) {
        int pp[NSUB];
#pragma unroll
        for (int m = 0; m < NSUB; ++m) pp[m] = 0;
        float dm = INF;
        for (int s = 0; s < KNN; ++s) {
            dm = INF;
            int sel = 0;
#pragma unroll
            for (int m = 0; m < NSUB; ++m) {
                const float v = smd[(pp[m] * NSUB + m) * QPB + tid];
                const bool w = v < dm;
                dm = w ? v : dm;
                sel = w ? m : sel;
            }
#pragma unroll
            for (int m = 0; m < NSUB; ++m) pp[m] += (sel == m);
        }
        d16[tid] = dm;
    }
    __syncthreads();   // smd dead below; slist overlays it

    // ---- P3: rescan, collect all candidates with d <= d16 (>=16, ~16-17)
    const float dt = d16[q];
    for (int jj = 0; jj < CPL; ++jj) {
        const int j = jbase + jj;
        const float px = ps[jj * 3 + 0];
        const float py = ps[jj * 3 + 1];
        const float pz = ps[jj * 3 + 2];
        const float dx = qx - px;
        const float dy = qy - py;
        const float dz = qz - pz;
        const float d = __fadd_rn(__fadd_rn(__fmul_rn(dx, dx), __fmul_rn(dy, dy)),
                                  __fmul_rn(dz, dz));
        const bool pass = (d <= dt) && (j != qg0);
        if (pass) {
            const unsigned pos = atomicAdd(&scnt[q], 1u);
            if (pos < LCAP)
                slist[pos * QPB + q] =
                    (((unsigned long long)__float_as_uint(d)) << 32) | (unsigned)j;
        }
    }
    __syncthreads();

    // ---- P4: per-query exact top-16 by u64 key = (d_bits, j); keys distinct
    if (tid < QPB) {
        const int c = min((int)scnt[tid], LCAP);
        unsigned long long prev = 0ULL;
        for (int s = 0; s < KNN; ++s) {
            unsigned long long best = ~0ULL;
            for (int i = 0; i < c; ++i) {
                const unsigned long long k = slist[i * QPB + tid];
                if (k >= prev && k < best) best = k;
            }
            sidx[tid * KNN + s] = (unsigned short)(best & 0xFFFFULL);
            prev = best + 1ULL;
        }
    }
    __syncthreads();

    // ---- P5: gather + write: 64 q x 16 k x 32 float4 = 32768 float4 per block
    const float* __restrict__ fb = features + (size_t)b * NPTS * FDIM;
    float* __restrict__ ob = out + (size_t)b * NPTS * (KNN * 2 * FDIM);
#pragma unroll 2
    for (int it = 0; it < 64; ++it) {
        const int flat = it * THREADS + tid;
        const int c4 = flat & 31;          // float4 column 0..31
        const int k = (flat >> 5) & 15;
        const int qq = flat >> 9;          // 0..63
        const int qg = qbase + qq;
        const int row = (c4 < 16) ? qg : (int)sidx[qq * KNN + k];
        const float4 v = *(const float4*)(fb + (size_t)row * FDIM + ((c4 & 15) << 2));
        *(float4*)(ob + (((size_t)(qg * KNN + k)) << 7) + (c4 << 2)) = v;
    }
}

extern "C" void kernel_launch(void* const* d_in, const int* in_sizes, int n_in,
                              void* d_out, int out_size, void* d_ws, size_t ws_size,
                              hipStream_t stream) {
    const float* points = (const float*)d_in[0];
    const float* features = (const float*)d_in[1];
    float* out = (float*)d_out;
    const int grid = BATCH * (NPTS / QPB);   // 512 blocks
    knn_kernel<<<dim3(grid), dim3(THREADS), 0, stream>>>(points, features, out);
}

// Round 7
// 348.559 us; speedup vs baseline: 2.4601x; 1.4866x over previous
//
#include <hip/hip_runtime.h>

// KNN: points (8,4096,3) f32, features (8,4096,64) f32.
// out (8,4096,16,128) f32: [center 64 | knn 64] per (b, i, k).
// Neighbors = 16 nearest excluding self, ascending distance, ties -> lower index.
//
// R5 post-mortem: VALU-bound (65% busy) on the 31-instr insert network that
// runs ~every iteration (wave-coherent), occupancy grid-capped at 4 waves/SIMD.
// R6/R7: radix-histogram select. Scan1 histograms monotone f32-bit buckets
// (5 VALU/candidate, no insert network); prefix finds bucket of the 16th
// distance; scan2 collects bucket<=B16 (superset, ~16-20) as u64 (d_bits,j)
// keys; exact final select unchanged. NSUB=16 -> 1024-thr blocks, 8 waves/SIMD.

#define BATCH 8
#define NPTS 4096
#define FDIM 64
#define KNN 16
#define QPB 64
#define NSUB 16
#define CPL (NPTS / NSUB)      // 256 candidates per thread
#define THREADS (QPB * NSUB)   // 1024
#define LCAP 48                // per-query recovery-list capacity (>= 16 + slack)
#define HSTRIDE 129            // hist row stride (u32); slot 128 = self (dead)
#define BUCKC 920              // (127-12)*8: bucket 0 starts at d = 2^-12
#define INF __builtin_inff()

__global__ __launch_bounds__(THREADS, 4)
void knn_kernel(const float* __restrict__ points,
                const float* __restrict__ features,
                float* __restrict__ out) {
    // LDS (35584 B):
    //  [0, 33024)     union { hist u32[QPB][HSTRIDE] (scan1/prefix) ;
    //                         slist u64[LCAP][QPB]   (scan2/select) }  // [i][q]
    //  [33024, 33280) b16  u32[QPB]   first bucket with cum >= 16
    //  [33280, 33536) scnt u32[QPB]
    //  [33536, 35584) sidx u16[QPB][KNN]
    __shared__ __align__(16) unsigned char smem[35584];
    unsigned* hist = (unsigned*)smem;
    unsigned long long* slist = (unsigned long long*)smem;
    unsigned* b16 = (unsigned*)(smem + 33024);
    unsigned* scnt = (unsigned*)(smem + 33280);
    unsigned short* sidx = (unsigned short*)(smem + 33536);

    const int tid = threadIdx.x;
    const int b = blockIdx.x >> 6;
    const int qbase = (blockIdx.x & 63) << 6;
    const float* pb = points + (size_t)b * NPTS * 3;

    const int q = tid & (QPB - 1);     // query within block (lane id)
    const int sub = tid >> 6;          // partition 0..15, uniform per wave
    const int qg0 = qbase + q;

    // clear hist + scnt
    for (int i = tid; i < QPB * HSTRIDE; i += THREADS) hist[i] = 0;
    if (tid < QPB) scnt[tid] = 0;

    const float qx = pb[qg0 * 3 + 0];
    const float qy = pb[qg0 * 3 + 1];
    const float qz = pb[qg0 * 3 + 2];

    const int jbase = __builtin_amdgcn_readfirstlane(sub) * CPL;
    const float* __restrict__ ps = pb + (size_t)jbase * 3;
    const int hrow = q * HSTRIDE;

    __syncthreads();

    // ---- scan1: histogram of monotone f32-bit buckets ----
    // bucket = clamp((bits(d)>>20) - 920, 0, 127): 8 buckets/octave over
    // d in [2^-12, 2^4). d>=0 always, so the map is monotone in d.
#pragma unroll 4
    for (int jj = 0; jj < CPL; ++jj) {
        const int j = jbase + jj;
        const float px = ps[jj * 3 + 0];
        const float py = ps[jj * 3 + 1];
        const float pz = ps[jj * 3 + 2];
        const float dx = qx - px;
        const float dy = qy - py;
        const float dz = qz - pz;
        // match numpy: ((dx*dx + dy*dy) + dz*dz), no FMA contraction
        const float d = __fadd_rn(__fadd_rn(__fmul_rn(dx, dx), __fmul_rn(dy, dy)),
                                  __fmul_rn(dz, dz));
        int bk = (int)(__float_as_uint(d) >> 20) - BUCKC;
        bk = min(127, max(0, bk));
        bk = (j == qg0) ? 128 : bk;    // self -> dead slot, branchless
        atomicAdd(&hist[hrow + bk], 1u);
    }
    __syncthreads();

    // ---- prefix: B16 = first bucket with cumulative count >= 16 ----
    if (tid < QPB) {
        unsigned c = 0;
        int bsel = 0;
#pragma unroll 8
        for (int bb = 0; bb < 128; ++bb) {
            c += hist[tid * HSTRIDE + bb];
            bsel += (c < KNN);
        }
        b16[tid] = (unsigned)bsel;     // cum(127) = 4095 >= 16 always
    }
    __syncthreads();   // hist dead below; slist overlays it

    // ---- scan2: collect all candidates with bucket <= B16 ----
    const int myB = (int)b16[q];
    for (int jj = 0; jj < CPL; ++jj) {
        const int j = jbase + jj;
        const float px = ps[jj * 3 + 0];
        const float py = ps[jj * 3 + 1];
        const float pz = ps[jj * 3 + 2];
        const float dx = qx - px;
        const float dy = qy - py;
        const float dz = qz - pz;
        const float d = __fadd_rn(__fadd_rn(__fmul_rn(dx, dx), __fmul_rn(dy, dy)),
                                  __fmul_rn(dz, dz));
        int bk = (int)(__float_as_uint(d) >> 20) - BUCKC;
        bk = min(127, max(0, bk));
        const bool pass = (bk <= myB) && (j != qg0);
        if (pass) {
            const unsigned pos = atomicAdd(&scnt[q], 1u);
            if (pos < LCAP)
                slist[pos * QPB + q] =
                    (((unsigned long long)__float_as_uint(d)) << 32) | (unsigned)j;
        }
    }
    __syncthreads();

    // ---- exact top-16 by u64 key = (d_bits, j); ties -> lower j ----
    if (tid < QPB) {
        const int c = min((int)scnt[tid], LCAP);
        unsigned long long prev = 0ULL;
        for (int s = 0; s < KNN; ++s) {
            unsigned long long best = ~0ULL;
            for (int i = 0; i < c; ++i) {
                const unsigned long long k = slist[i * QPB + tid];
                if (k >= prev && k < best) best = k;
            }
            sidx[tid * KNN + s] = (unsigned short)(best & 0xFFFFULL);
            prev = best + 1ULL;
        }
    }
    __syncthreads();

    // ---- gather + write: 64 q x 16 k x 32 float4 = 32768 float4 per block ----
    const float* __restrict__ fb = features + (size_t)b * NPTS * FDIM;
    float* __restrict__ ob = out + (size_t)b * NPTS * (KNN * 2 * FDIM);
#pragma unroll 2
    for (int it = 0; it < 32; ++it) {
        const int flat = it * THREADS + tid;
        const int c4 = flat & 31;          // float4 column 0..31
        const int k = (flat >> 5) & 15;
        const int qq = flat >> 9;          // 0..63
        const int qg = qbase + qq;
        const int row = (c4 < 16) ? qg : (int)sidx[qq * KNN + k];
        const float4 v = *(const float4*)(fb + (size_t)row * FDIM + ((c4 & 15) << 2));
        *(float4*)(ob + (((size_t)(qg * KNN + k)) << 7) + (c4 << 2)) = v;
    }
}

extern "C" void kernel_launch(void* const* d_in, const int* in_sizes, int n_in,
                              void* d_out, int out_size, void* d_ws, size_t ws_size,
                              hipStream_t stream) {
    const float* points = (const float*)d_in[0];
    const float* features = (const float*)d_in[1];
    float* out = (float*)d_out;
    const int grid = BATCH * (NPTS / QPB);   // 512 blocks x 1024 threads
    knn_kernel<<<dim3(grid), dim3(THREADS), 0, stream>>>(points, features, out);
}

// Round 8
// 341.863 us; speedup vs baseline: 2.5082x; 1.0196x over previous
//
#include <hip/hip_runtime.h>

// KNN: points (8,4096,3) f32, features (8,4096,64) f32.
// out (8,4096,16,128) f32: [center 64 | knn 64] per (b, i, k).
// Neighbors = 16 nearest excluding self, ascending distance, ties -> lower index.
//
// R7 post-mortem: kernel ~143us (below the 163us fill kernels in top-5).
// R8 trims: (1) self-exclusion is free -- self d=0 always lands in bucket 0 /
// smallest u64 key, so scans drop the j==qg0 checks; prefix needs cum>=17;
// select takes 17 and skips rank 0. (2) scan2 membership = single uint compare
// bits(d) < ubound, ubound=(B16+921)<<20 precomputed per query. (3) med3 clamp.

#define BATCH 8
#define NPTS 4096
#define FDIM 64
#define KNN 16
#define QPB 64
#define NSUB 16
#define CPL (NPTS / NSUB)      // 256 candidates per thread
#define THREADS (QPB * NSUB)   // 1024
#define LCAP 48                // per-query recovery-list capacity (17 + slack)
#define HSTRIDE 129            // hist row stride (u32), odd -> bank spread
#define BUCKC 920              // (bits>>20)-920: bucket 0 starts at d = 2^-12
#define NSEL 17                // self + 16 neighbors

__global__ __launch_bounds__(THREADS, 4)
void knn_kernel(const float* __restrict__ points,
                const float* __restrict__ features,
                float* __restrict__ out) {
    // LDS (35584 B):
    //  [0, 33024)     union { hist u32[QPB][HSTRIDE] (scan1/prefix) ;
    //                         slist u64[LCAP][QPB]   (scan2/select) }  // [i][q]
    //  [33024, 33280) ubnd u32[QPB]   exclusive upper bound on bits(d)
    //  [33280, 33536) scnt u32[QPB]
    //  [33536, 35584) sidx u16[QPB][KNN]
    __shared__ __align__(16) unsigned char smem[35584];
    unsigned* hist = (unsigned*)smem;
    unsigned long long* slist = (unsigned long long*)smem;
    unsigned* ubnd = (unsigned*)(smem + 33024);
    unsigned* scnt = (unsigned*)(smem + 33280);
    unsigned short* sidx = (unsigned short*)(smem + 33536);

    const int tid = threadIdx.x;
    const int b = blockIdx.x >> 6;
    const int qbase = (blockIdx.x & 63) << 6;
    const float* pb = points + (size_t)b * NPTS * 3;

    const int q = tid & (QPB - 1);     // query within block (lane id)
    const int sub = tid >> 6;          // partition 0..15, uniform per wave
    const int qg0 = qbase + q;

    // clear hist + scnt
    for (int i = tid; i < QPB * HSTRIDE; i += THREADS) hist[i] = 0;
    if (tid < QPB) scnt[tid] = 0;

    const float qx = pb[qg0 * 3 + 0];
    const float qy = pb[qg0 * 3 + 1];
    const float qz = pb[qg0 * 3 + 2];

    const int jbase = __builtin_amdgcn_readfirstlane(sub) * CPL;
    const float* __restrict__ ps = pb + (size_t)jbase * 3;
    const int hrow = q * HSTRIDE;

    __syncthreads();

    // ---- scan1: histogram of monotone f32-bit buckets (self included: d=0
    // always lands in bucket 0, accounted for by the cum>=17 prefix) ----
#pragma unroll 4
    for (int jj = 0; jj < CPL; ++jj) {
        const float px = ps[jj * 3 + 0];
        const float py = ps[jj * 3 + 1];
        const float pz = ps[jj * 3 + 2];
        const float dx = qx - px;
        const float dy = qy - py;
        const float dz = qz - pz;
        // match numpy: ((dx*dx + dy*dy) + dz*dz), no FMA contraction
        const float d = __fadd_rn(__fadd_rn(__fmul_rn(dx, dx), __fmul_rn(dy, dy)),
                                  __fmul_rn(dz, dz));
        int bk = (int)(__float_as_uint(d) >> 20) - BUCKC;
        bk = min(127, max(0, bk));     // v_med3_i32
        atomicAdd(&hist[hrow + bk], 1u);
    }
    __syncthreads();

    // ---- prefix: B16 = first bucket with cumulative count >= 17 (incl self);
    // store exclusive uint upper bound on bits(d) for scan2 ----
    if (tid < QPB) {
        unsigned c = 0;
        int bsel = 0;
#pragma unroll 8
        for (int bb = 0; bb < 128; ++bb) {
            c += hist[tid * HSTRIDE + bb];
            bsel += (c < NSEL);
        }
        // bucket bsel's exclusive upper edge; bsel==127 -> accept all finite
        ubnd[tid] = (bsel >= 127) ? 0x7f800000u
                                  : ((unsigned)(bsel + 1 + BUCKC) << 20);
    }
    __syncthreads();   // hist dead below; slist overlays it

    // ---- scan2: collect all candidates with bits(d) < ubound ----
    const unsigned ub = ubnd[q];
    const unsigned pbase2 = (unsigned)q;   // slist column
#pragma unroll 4
    for (int jj = 0; jj < CPL; ++jj) {
        const float px = ps[jj * 3 + 0];
        const float py = ps[jj * 3 + 1];
        const float pz = ps[jj * 3 + 2];
        const float dx = qx - px;
        const float dy = qy - py;
        const float dz = qz - pz;
        const float d = __fadd_rn(__fadd_rn(__fmul_rn(dx, dx), __fmul_rn(dy, dy)),
                                  __fmul_rn(dz, dz));
        const unsigned dbits = __float_as_uint(d);
        if (dbits < ub) {
            const unsigned pos = atomicAdd(&scnt[q], 1u);
            if (pos < LCAP)
                slist[pos * QPB + pbase2] =
                    (((unsigned long long)dbits) << 32) | (unsigned)(jbase + jj);
        }
    }
    __syncthreads();

    // ---- exact top-17 by u64 key = (d_bits, j); rank 0 is self (d=0,
    // strictly unique since points are distinct); store ranks 1..16 ----
    if (tid < QPB) {
        const int c = min((int)scnt[tid], LCAP);
        unsigned long long prev = 0ULL;
        for (int s = 0; s < NSEL; ++s) {
            unsigned long long best = ~0ULL;
            for (int i = 0; i < c; ++i) {
                const unsigned long long k = slist[i * QPB + tid];
                if (k >= prev && k < best) best = k;
            }
            if (s > 0)
                sidx[tid * KNN + (s - 1)] = (unsigned short)(best & 0xFFFFULL);
            prev = best + 1ULL;
        }
    }
    __syncthreads();

    // ---- gather + write: 64 q x 16 k x 32 float4 = 32768 float4 per block ----
    const float* __restrict__ fb = features + (size_t)b * NPTS * FDIM;
    float* __restrict__ ob = out + (size_t)b * NPTS * (KNN * 2 * FDIM);
#pragma unroll 2
    for (int it = 0; it < 32; ++it) {
        const int flat = it * THREADS + tid;
        const int c4 = flat & 31;          // float4 column 0..31
        const int k = (flat >> 5) & 15;
        const int qq = flat >> 9;          // 0..63
        const int qg = qbase + qq;
        const int row = (c4 < 16) ? qg : (int)sidx[qq * KNN + k];
        const float4 v = *(const float4*)(fb + (size_t)row * FDIM + ((c4 & 15) << 2));
        *(float4*)(ob + (((size_t)(qg * KNN + k)) << 7) + (c4 << 2)) = v;
    }
}

extern "C" void kernel_launch(void* const* d_in, const int* in_sizes, int n_in,
                              void* d_out, int out_size, void* d_ws, size_t ws_size,
                              hipStream_t stream) {
    const float* points = (const float*)d_in[0];
    const float* features = (const float*)d_in[1];
    float* out = (float*)d_out;
    const int grid = BATCH * (NPTS / QPB);   // 512 blocks x 1024 threads
    knn_kernel<<<dim3(grid), dim3(THREADS), 0, stream>>>(points, features, out);
}

// Round 10
// 334.048 us; speedup vs baseline: 2.5669x; 1.0234x over previous
//
#include <hip/hip_runtime.h>

// KNN: points (8,4096,3) f32, features (8,4096,64) f32.
// out (8,4096,16,128) f32: [center 64 | knn 64] per (b, i, k).
// Neighbors = 16 nearest excluding self, ascending distance, ties -> lower index.
//
// R9 fix: __builtin_nontemporal_store requires a clang vector type, not HIP's
// float4 class -> use ext_vector_type(4). Rest identical to R9:
// (A) parallel rank-select (all 1024 threads; rank = #smaller u64 keys;
// ranks unique -> write sidx[rank-1] directly). (B) scans use 3-op FMA
// distance with +1-bucket margin (9% >> 3ulp); exact rn-distance recomputed
// only for accepted candidates so final (d,j) order is bitwise-exact vs numpy.
// (D) nontemporal output stores (268MB >> L2, avoid write-allocate pollution).

typedef float f32x4 __attribute__((ext_vector_type(4)));

#define BATCH 8
#define NPTS 4096
#define FDIM 64
#define KNN 16
#define QPB 64
#define NSUB 16
#define CPL (NPTS / NSUB)      // 256 candidates per thread
#define THREADS (QPB * NSUB)   // 1024
#define LCAP 64                // per-query recovery-list capacity (~23 typ.)
#define HSTRIDE 129            // hist row stride (u32), odd -> bank spread
#define BUCKC 920              // (bits>>20)-920: bucket 0 starts at d = 2^-12
#define NSEL 17                // self + 16 neighbors

__global__ __launch_bounds__(THREADS, 4)
void knn_kernel(const float* __restrict__ points,
                const float* __restrict__ features,
                float* __restrict__ out) {
    // LDS (35584 B):
    //  [0, 33024)     union { hist u32[QPB][HSTRIDE] (scan1/prefix) ;
    //                         slist u64[LCAP][QPB]   (scan2/select) }  // [i][q]
    //  [33024, 33280) ubnd u32[QPB]   exclusive upper bound on bits(d_fma)
    //  [33280, 33536) scnt u32[QPB]
    //  [33536, 35584) sidx u16[QPB][KNN]
    __shared__ __align__(16) unsigned char smem[35584];
    unsigned* hist = (unsigned*)smem;
    unsigned long long* slist = (unsigned long long*)smem;
    unsigned* ubnd = (unsigned*)(smem + 33024);
    unsigned* scnt = (unsigned*)(smem + 33280);
    unsigned short* sidx = (unsigned short*)(smem + 33536);

    const int tid = threadIdx.x;
    const int b = blockIdx.x >> 6;
    const int qbase = (blockIdx.x & 63) << 6;
    const float* pb = points + (size_t)b * NPTS * 3;

    const int q = tid & (QPB - 1);     // query within block (lane id)
    const int sub = tid >> 6;          // partition 0..15, uniform per wave
    const int qg0 = qbase + q;

    // clear hist + scnt
    for (int i = tid; i < QPB * HSTRIDE; i += THREADS) hist[i] = 0;
    if (tid < QPB) scnt[tid] = 0;

    const float qx = pb[qg0 * 3 + 0];
    const float qy = pb[qg0 * 3 + 1];
    const float qz = pb[qg0 * 3 + 2];

    const int jbase = __builtin_amdgcn_readfirstlane(sub) * CPL;
    const float* __restrict__ ps = pb + (size_t)jbase * 3;
    const int hrow = q * HSTRIDE;

    __syncthreads();

    // ---- scan1: histogram of monotone f32-bit buckets of d_fma ----
    // d_fma = fma(dx,dx, fma(dy,dy, dz*dz)): 3 ops, same sequence as scan2
    // -> identical bits. Self (d=0) included; prefix accounts via cum>=17.
#pragma unroll 4
    for (int jj = 0; jj < CPL; ++jj) {
        const float px = ps[jj * 3 + 0];
        const float py = ps[jj * 3 + 1];
        const float pz = ps[jj * 3 + 2];
        const float dx = qx - px;
        const float dy = qy - py;
        const float dz = qz - pz;
        const float d = __fmaf_rn(dx, dx, __fmaf_rn(dy, dy, __fmul_rn(dz, dz)));
        int bk = (int)(__float_as_uint(d) >> 20) - BUCKC;
        bk = min(127, max(0, bk));     // v_med3_i32
        atomicAdd(&hist[hrow + bk], 1u);
    }
    __syncthreads();

    // ---- prefix: bsel = first bucket with cum >= 17 (by d_fma); threshold =
    // exclusive upper edge of bucket bsel+1 (margin bucket: 9% in d >> 3ulp
    // fma-vs-rn error) -> collected set provably contains the exact top-17 ----
    if (tid < QPB) {
        unsigned c = 0;
        int bsel = 0;
#pragma unroll 8
        for (int bb = 0; bb < 128; ++bb) {
            c += hist[tid * HSTRIDE + bb];
            bsel += (c < NSEL);
        }
        ubnd[tid] = (bsel + 1 >= 127) ? 0x7f800000u
                                      : ((unsigned)(bsel + 2 + BUCKC) << 20);
    }
    __syncthreads();   // hist dead below; slist overlays it

    // ---- scan2: collect candidates with bits(d_fma) < ubound; store EXACT
    // rn-distance (recomputed only on accept, ~20/query) for final ordering ----
    const unsigned ub = ubnd[q];
#pragma unroll 4
    for (int jj = 0; jj < CPL; ++jj) {
        const float px = ps[jj * 3 + 0];
        const float py = ps[jj * 3 + 1];
        const float pz = ps[jj * 3 + 2];
        const float dx = qx - px;
        const float dy = qy - py;
        const float dz = qz - pz;
        const float d = __fmaf_rn(dx, dx, __fmaf_rn(dy, dy, __fmul_rn(dz, dz)));
        if (__float_as_uint(d) < ub) {
            // match numpy: ((dx*dx + dy*dy) + dz*dz), no FMA contraction
            const float de = __fadd_rn(__fadd_rn(__fmul_rn(dx, dx), __fmul_rn(dy, dy)),
                                       __fmul_rn(dz, dz));
            const unsigned pos = atomicAdd(&scnt[q], 1u);
            if (pos < LCAP)
                slist[pos * QPB + q] =
                    (((unsigned long long)__float_as_uint(de)) << 32)
                    | (unsigned)(jbase + jj);
        }
    }
    __syncthreads();

    // ---- parallel rank-select: key rank = #keys smaller (u64 keys distinct;
    // exact (d_bits, j) order). rank 0 = dropped head; ranks 1..16 -> sidx.
    // All 1024 threads: thread (q, i=tid>>6) handles slots i, i+16, ... ----
    {
        const int c = min((int)scnt[q], LCAP);
        for (int slot = sub; slot < c; slot += NSUB) {
            const unsigned long long mykey = slist[slot * QPB + q];
            int rank = 0;
            for (int m = 0; m < c; ++m)
                rank += (slist[m * QPB + q] < mykey);
            if (rank >= 1 && rank <= KNN)
                sidx[q * KNN + (rank - 1)] = (unsigned short)(mykey & 0xFFFFULL);
        }
    }
    __syncthreads();

    // ---- gather + write: 64 q x 16 k x 32 float4 = 32768 float4 per block ----
    const float* __restrict__ fb = features + (size_t)b * NPTS * FDIM;
    float* __restrict__ ob = out + (size_t)b * NPTS * (KNN * 2 * FDIM);
#pragma unroll 2
    for (int it = 0; it < 32; ++it) {
        const int flat = it * THREADS + tid;
        const int c4 = flat & 31;          // float4 column 0..31
        const int k = (flat >> 5) & 15;
        const int qq = flat >> 9;          // 0..63
        const int qg = qbase + qq;
        const int row = (c4 < 16) ? qg : (int)sidx[qq * KNN + k];
        const f32x4 v = *(const f32x4*)(fb + (size_t)row * FDIM + ((c4 & 15) << 2));
        __builtin_nontemporal_store(
            v, (f32x4*)(ob + (((size_t)(qg * KNN + k)) << 7) + (c4 << 2)));
    }
}

extern "C" void kernel_launch(void* const* d_in, const int* in_sizes, int n_in,
                              void* d_out, int out_size, void* d_ws, size_t ws_size,
                              hipStream_t stream) {
    const float* points = (const float*)d_in[0];
    const float* features = (const float*)d_in[1];
    float* out = (float*)d_out;
    const int grid = BATCH * (NPTS / QPB);   // 512 blocks x 1024 threads
    knn_kernel<<<dim3(grid), dim3(THREADS), 0, stream>>>(points, features, out);
}